// Round 3
// baseline (995.376 us; speedup 1.0000x reference)
//
#include <hip/hip_runtime.h>
#include <hip/hip_bf16.h>
#include <math.h>

#define BB 4
#define NN 300
#define TOP 36
#define CC 2048
#define DD 2048
#define CONF_T 0.3f
#define IOU_T 0.7f

// ---- workspace layout (bytes) ----
// [0,16)      int nvalid[4]
// [256,2560)  float wlbox[144][4]
// [2560,3136) int wllev[144]
// [3200,3776) int wlpos[144]
// [4096, +144*2048*4) float pooled[144][2048]  (row = b*36 + outpos)
#define WS_BOX 256
#define WS_LEV 2560
#define WS_POS 3200
#define WS_POOLED 4096

// =====================================================================
// Kernel 1: per-image confidence filter + greedy NMS + level/order calc
// =====================================================================
__global__ __launch_bounds__(512) void select_kernel(
    const float* __restrict__ boxes, const float* __restrict__ scores,
    int* __restrict__ nvalid, float* __restrict__ wlbox,
    int* __restrict__ wllev, int* __restrict__ wlpos)
{
    int b = blockIdx.x;
    int t = threadIdx.x;
    __shared__ float raw[NN];
    __shared__ float ss[NN];
    __shared__ float bx[NN][4];
    __shared__ float area[NN];
    __shared__ unsigned long long sup[NN][5];
    __shared__ int slots[TOP];

    if (t < NN) raw[t] = scores[b * NN + t];
    __syncthreads();

    // stable descending rank (matches jnp.argsort(-scores))
    if (t < NN) {
        float si = raw[t];
        int r = 0;
        for (int j = 0; j < NN; ++j) {
            float sj = raw[j];
            r += (sj > si) || (sj == si && j < t);
        }
        ss[r] = si;
        const float* bp = boxes + (size_t)(b * NN + t) * 4;
        float x1 = bp[0], y1 = bp[1], x2 = bp[2], y2 = bp[3];
        bx[r][0] = x1; bx[r][1] = y1; bx[r][2] = x2; bx[r][3] = y2;
        area[r] = (x2 - x1) * (y2 - y1);
    }
    __syncthreads();

    // suppression matrix: sup[i] bit j = (iou(i,j) > T) && (j > i)
    int wave = t >> 6, lane = t & 63;
    for (int i = wave; i < NN; i += 8) {
        float ix1 = bx[i][0], iy1 = bx[i][1], ix2 = bx[i][2], iy2 = bx[i][3];
        float ia = area[i];
        for (int jw = 0; jw < 5; ++jw) {
            int j = jw * 64 + lane;
            bool s = false;
            if (j < NN) {
                float xx1 = fmaxf(ix1, bx[j][0]);
                float yy1 = fmaxf(iy1, bx[j][1]);
                float xx2 = fminf(ix2, bx[j][2]);
                float yy2 = fminf(iy2, bx[j][3]);
                float inter = fmaxf(xx2 - xx1, 0.0f) * fmaxf(yy2 - yy1, 0.0f);
                float iou = inter / (ia + area[j] - inter);
                s = (iou > IOU_T) && (j > i);
            }
            unsigned long long m = __ballot(s);
            if (lane == 0) sup[i][jw] = m;
        }
    }
    __syncthreads();

    if (t == 0) {
        unsigned long long kw[5] = {0ull, 0ull, 0ull, 0ull, 0ull};
        for (int r = 0; r < NN; ++r)
            if (ss[r] > CONF_T) kw[r >> 6] |= (1ull << (r & 63));
        for (int i = 0; i < NN; ++i) {
            if ((kw[i >> 6] >> (i & 63)) & 1ull) {
                kw[0] &= ~sup[i][0]; kw[1] &= ~sup[i][1]; kw[2] &= ~sup[i][2];
                kw[3] &= ~sup[i][3]; kw[4] &= ~sup[i][4];
            }
        }
        int cnt = 0;
        for (int r = 0; r < NN && cnt < TOP; ++r)
            if ((kw[r >> 6] >> (r & 63)) & 1ull) slots[cnt++] = r;
        nvalid[b] = cnt;

        int key[TOP];
        for (int j = 0; j < cnt; ++j) {
            int r = slots[j];
            float dx = bx[r][2] - bx[r][0];
            float dy = bx[r][3] - bx[r][1];
            float diag = sqrtf(dx * dx + dy * dy);
            float lv = floorf(4.0f + log2f(diag / 224.0f * 4.0f));
            lv = fminf(fmaxf(lv, 2.0f), 5.0f);
            int lev = (int)lv - 2;
            key[j] = lev * TOP + j;
            int s = b * TOP + j;
            wlbox[s * 4 + 0] = bx[r][0];
            wlbox[s * 4 + 1] = bx[r][1];
            wlbox[s * 4 + 2] = bx[r][2];
            wlbox[s * 4 + 3] = bx[r][3];
            wllev[s] = lev;
        }
        for (int j = 0; j < cnt; ++j) {
            int p = 0;
            for (int j2 = 0; j2 < cnt; ++j2) p += key[j2] < key[j];
            wlpos[b * TOP + j] = p;
        }
    }
}

// =====================================================================
// Kernel 2: ROIAlign(7x7,sr=2)+global-avg as rank-1 weighted reduction.
// block = (box slot, 256-channel chunk); lanes = x positions (coalesced)
// =====================================================================
__global__ __launch_bounds__(256) void roi_kernel(
    const float* __restrict__ f0, const float* __restrict__ f1,
    const float* __restrict__ f2, const float* __restrict__ f3,
    const int* __restrict__ nvalid, const float* __restrict__ wlbox,
    const int* __restrict__ wllev, const int* __restrict__ wlpos,
    float* __restrict__ pooled)
{
    int slot = blockIdx.x;
    int b = slot / TOP, j = slot % TOP;
    if (j >= nvalid[b]) return;

    __shared__ int rowY[64];
    __shared__ float rowW[64];
    __shared__ float colW[64];
    __shared__ int s_nrows, s_xlo, s_lev, s_pos;

    int t = threadIdx.x;
    if (t < 64) { rowW[t] = 0.0f; colW[t] = 0.0f; }
    __syncthreads();

    if (t == 0) {
        float x1 = wlbox[slot * 4 + 0], y1 = wlbox[slot * 4 + 1];
        float x2 = wlbox[slot * 4 + 2], y2 = wlbox[slot * 4 + 3];
        int lev = wllev[slot];
        s_lev = lev;
        s_pos = wlpos[slot];
        int H = (lev == 0) ? 100 : (lev == 1) ? 50 : (lev == 2) ? 25 : 13;
        float rw = fmaxf(x2 - x1, 1.0f);
        float rh = fmaxf(y2 - y1, 1.0f);

        // ----- y taps -----
        int ylo = 1 << 30;
        for (int i = 0; i < 14; ++i) {
            float ysv = y1 + (float)(i / 2) * (rh / 7.0f) + ((float)(i % 2) + 0.5f) * (rh / 14.0f);
            float y = fminf(fmaxf(ysv, 0.0f), (float)H - 1.0f);
            int y0 = (int)floorf(y);
            if (y0 < ylo) ylo = y0;
        }
        for (int i = 0; i < 14; ++i) {
            float ysv = y1 + (float)(i / 2) * (rh / 7.0f) + ((float)(i % 2) + 0.5f) * (rh / 14.0f);
            bool yout = (ysv < -1.0f) || (ysv > (float)H);
            float y = fminf(fmaxf(ysv, 0.0f), (float)H - 1.0f);
            float y0f = floorf(y);
            int y0 = (int)y0f;
            float wy = y - y0f;
            int y1i = min(y0 + 1, H - 1);
            if (!yout) {
                rowW[y0 - ylo] += (1.0f - wy);
                rowW[y1i - ylo] += wy;
            }
        }
        int n = 0;
        for (int k = 0; k < 64; ++k) {
            float w = rowW[k];
            if (w != 0.0f) { rowY[n] = ylo + k; rowW[n] = w; ++n; }
        }
        s_nrows = n;

        // ----- x taps (dense, lane-indexed) -----
        int xlo = 1 << 30;
        for (int i = 0; i < 14; ++i) {
            float xsv = x1 + (float)(i / 2) * (rw / 7.0f) + ((float)(i % 2) + 0.5f) * (rw / 14.0f);
            float x = fminf(fmaxf(xsv, 0.0f), (float)H - 1.0f);
            int x0 = (int)floorf(x);
            if (x0 < xlo) xlo = x0;
        }
        for (int i = 0; i < 14; ++i) {
            float xsv = x1 + (float)(i / 2) * (rw / 7.0f) + ((float)(i % 2) + 0.5f) * (rw / 14.0f);
            bool xout = (xsv < -1.0f) || (xsv > (float)H);
            float x = fminf(fmaxf(xsv, 0.0f), (float)H - 1.0f);
            float x0f = floorf(x);
            int x0 = (int)x0f;
            float wx = x - x0f;
            int x1i = min(x0 + 1, H - 1);
            if (!xout) {
                colW[x0 - xlo] += (1.0f - wx);
                colW[x1i - xlo] += wx;
            }
        }
        s_xlo = xlo;
    }
    __syncthreads();

    int lev = s_lev;
    int H = (lev == 0) ? 100 : (lev == 1) ? 50 : (lev == 2) ? 25 : 13;
    const float* fm = (lev == 0) ? f0 : (lev == 1) ? f1 : (lev == 2) ? f2 : f3;
    size_t plane = (size_t)H * (size_t)H;
    fm += (size_t)b * CC * plane;

    int lane = t & 63, wave = t >> 6;
    int c0 = blockIdx.y * 256 + wave * 64;
    int nrows = s_nrows;
    int xlo = s_xlo;
    float cw = colW[lane];
    bool act = (cw != 0.0f);
    float* prow = pooled + (size_t)(b * TOP + s_pos) * DD;

    for (int cci = 0; cci < 64; ++cci) {
        int c = c0 + cci;
        const float* p = fm + (size_t)c * plane + xlo + lane;
        float acc = 0.0f;
        for (int r = 0; r < nrows; ++r) {
            float v = act ? p[rowY[r] * H] : 0.0f;
            acc = fmaf(rowW[r], v, acc);
        }
        float v2 = acc * cw;
        #pragma unroll
        for (int o = 32; o > 0; o >>= 1) v2 += __shfl_xor(v2, o);
        if (lane == 0) prow[c] = v2 * (1.0f / 196.0f);
    }
}

// =====================================================================
// Kernel 3: out[m,d] = valid ? pooled[m,:]·W[d,:] + bias[d] : 0
// M=144, N=2048, K=2048.  BM=16 BN=128 BK=32, 256 threads.
// =====================================================================
#define BM 16
#define BN 128
#define BK 32
__global__ __launch_bounds__(256) void gemm_kernel(
    const float* __restrict__ Apool, const float* __restrict__ Wg,
    const float* __restrict__ bias, const int* __restrict__ nvalid,
    float* __restrict__ out)
{
    __shared__ float As[BK][BM + 1];
    __shared__ float Bs[BK][BN + 1];
    int t = threadIdx.x;
    int m0 = blockIdx.x * BM;
    int n0 = blockIdx.y * BN;
    int dlane = t & 31;          // owns d = n0 + dlane + 32k, k=0..3
    int mi0 = (t >> 5) * 2;      // owns rows mi0, mi0+1
    float acc[2][4] = {};

    for (int k0 = 0; k0 < CC; k0 += BK) {
        {
            int lin = t * 2;
            int cA = lin & 31, iA = lin >> 5;
            const float* src = Apool + (size_t)(m0 + iA) * CC + k0 + cA;
            As[cA][iA] = src[0];
            As[cA + 1][iA] = src[1];
        }
        #pragma unroll
        for (int l = 0; l < 16; ++l) {
            int lin = t + l * 256;
            int cB = lin & 31, dB = lin >> 5;
            Bs[cB][dB] = Wg[(size_t)(n0 + dB) * CC + k0 + cB];
        }
        __syncthreads();
        #pragma unroll
        for (int cc = 0; cc < BK; ++cc) {
            float a0 = As[cc][mi0];
            float a1 = As[cc][mi0 + 1];
            float b0 = Bs[cc][dlane];
            float b1 = Bs[cc][dlane + 32];
            float b2 = Bs[cc][dlane + 64];
            float b3 = Bs[cc][dlane + 96];
            acc[0][0] = fmaf(a0, b0, acc[0][0]);
            acc[0][1] = fmaf(a0, b1, acc[0][1]);
            acc[0][2] = fmaf(a0, b2, acc[0][2]);
            acc[0][3] = fmaf(a0, b3, acc[0][3]);
            acc[1][0] = fmaf(a1, b0, acc[1][0]);
            acc[1][1] = fmaf(a1, b1, acc[1][1]);
            acc[1][2] = fmaf(a1, b2, acc[1][2]);
            acc[1][3] = fmaf(a1, b3, acc[1][3]);
        }
        __syncthreads();
    }

    #pragma unroll
    for (int ii = 0; ii < 2; ++ii) {
        int m = m0 + mi0 + ii;
        int bimg = m / TOP, pos = m % TOP;
        bool valid = pos < nvalid[bimg];
        float* orow = out + (size_t)m * DD + n0;
        #pragma unroll
        for (int k = 0; k < 4; ++k) {
            int d = dlane + 32 * k;
            orow[d] = valid ? (acc[ii][k] + bias[n0 + d]) : 0.0f;
        }
    }
}

extern "C" void kernel_launch(void* const* d_in, const int* in_sizes, int n_in,
                              void* d_out, int out_size, void* d_ws, size_t ws_size,
                              hipStream_t stream) {
    (void)in_sizes; (void)n_in; (void)out_size; (void)ws_size;
    const float* boxes  = (const float*)d_in[0];
    const float* scores = (const float*)d_in[1];
    const float* f0     = (const float*)d_in[2];
    const float* f1     = (const float*)d_in[3];
    const float* f2     = (const float*)d_in[4];
    const float* f3     = (const float*)d_in[5];
    const float* Wg     = (const float*)d_in[6];
    const float* bias   = (const float*)d_in[7];
    float* out = (float*)d_out;
    char* ws = (char*)d_ws;

    int*   nvalid = (int*)(ws + 0);
    float* wlbox  = (float*)(ws + WS_BOX);
    int*   wllev  = (int*)(ws + WS_LEV);
    int*   wlpos  = (int*)(ws + WS_POS);
    float* pooled = (float*)(ws + WS_POOLED);

    select_kernel<<<dim3(BB), dim3(512), 0, stream>>>(boxes, scores, nvalid, wlbox, wllev, wlpos);
    roi_kernel<<<dim3(BB * TOP, 8), dim3(256), 0, stream>>>(f0, f1, f2, f3, nvalid, wlbox, wllev, wlpos, pooled);
    gemm_kernel<<<dim3((BB * TOP) / BM, DD / BN), dim3(256), 0, stream>>>(pooled, Wg, bias, nvalid, out);
}